// Round 3
// baseline (2889.469 us; speedup 1.0000x reference)
//
#include <hip/hip_runtime.h>

// ---------------------------------------------------------------------------
// Graph-conv LSTM encoder, B=4 T=12 N=4096 F=32, NG=14 gates.
// R5: R2 skeleton (split-K GEMM, LDS-staged B, 4 blocks/CU) with:
//  - atomic epilogue replaced by coalesced per-slice partial tiles (16 KB)
//  - gates fused into the GEMM kernel via split-K ticket (last of 4 slice
//    blocks per row-tile sums partials and runs the gate math inline)
//  - B loads issued before A loads in each stage
// Dispatches: 53 -> 29. m bf16 panel double-buffered by t parity.
// ---------------------------------------------------------------------------

typedef __bf16 bf16_t;
typedef __bf16 bf16x8 __attribute__((ext_vector_type(8)));
typedef float  f32x4  __attribute__((ext_vector_type(4)));

#define DI __device__ __forceinline__

#define BB 4
#define TT 12
#define NN 4096
#define FF 32

DI float sigm(float x)  { return __builtin_amdgcn_rcpf(1.f + __expf(-x)); }
DI float tanh_f(float x){ float e = __expf(2.f * x); return 1.f - 2.f * __builtin_amdgcn_rcpf(e + 1.f); }

// ---------------- adj fp32 -> bf16 (8 elements / thread) --------------------
__global__ __launch_bounds__(256) void conv_adj_k(const float* __restrict__ a,
                                                  bf16_t* __restrict__ o) {
    size_t i = ((size_t)blockIdx.x * 256 + threadIdx.x) * 8;
    float4 v0 = *(const float4*)(a + i);
    float4 v1 = *(const float4*)(a + i + 4);
    union { uint4 u; bf16_t h[8]; } t;
    t.h[0] = (bf16_t)v0.x; t.h[1] = (bf16_t)v0.y; t.h[2] = (bf16_t)v0.z; t.h[3] = (bf16_t)v0.w;
    t.h[4] = (bf16_t)v1.x; t.h[5] = (bf16_t)v1.y; t.h[6] = (bf16_t)v1.z; t.h[7] = (bf16_t)v1.w;
    *(uint4*)(o + i) = t.u;
}

// ---------------- x [B,T,N,F] fp32 -> xT [B, T*F, N] bf16 -------------------
__global__ __launch_bounds__(256) void xpose_k(const float* __restrict__ x,
                                               bf16_t* __restrict__ xT) {
    const int b = blockIdx.z, t = blockIdx.y, n0 = blockIdx.x * 64;
    const int tid = threadIdx.x;
    __shared__ float tile[64][33];
    const float* src = x + (((size_t)(b * TT + t)) * NN + n0) * FF;
#pragma unroll
    for (int rr = 0; rr < 2; ++rr) {
        int idx = rr * 256 + tid;
        int row = idx >> 3, seg = idx & 7;
        float4 v = *(const float4*)(src + row * FF + seg * 4);
        tile[row][seg * 4 + 0] = v.x; tile[row][seg * 4 + 1] = v.y;
        tile[row][seg * 4 + 2] = v.z; tile[row][seg * 4 + 3] = v.w;
    }
    __syncthreads();
    const int f = tid >> 3, seg = tid & 7;
    union { uint4 u; bf16_t h[8]; } o;
#pragma unroll
    for (int j = 0; j < 8; ++j) o.h[j] = (bf16_t)tile[seg * 8 + j][f];
    *(uint4*)&xT[((size_t)(b * 384 + t * FF + f)) * NN + n0 + seg * 8] = o.u;
}

// ---------------- W [14,32,64] fp32 -> MFMA B-fragments bf16 ----------------
__global__ __launch_bounds__(256) void make_wfrag_k(const float* __restrict__ W,
                                                    bf16_t* __restrict__ Wf) {
    const int g = blockIdx.x, tid = threadIdx.x;
    const int ct = tid >> 6, lane = tid & 63;
    const int k0 = (lane >> 4) * 8, col = ct * 16 + (lane & 15);
    union { uint4 u; bf16_t h[8]; } t;
#pragma unroll
    for (int j = 0; j < 8; ++j) t.h[j] = (bf16_t)W[(g * 32 + k0 + j) * 64 + col];
    *(uint4*)&Wf[((g * 4 + ct) * 64 + lane) * 8] = t.u;
}

// ---------------- init: h=1, m panel=1, c=m=1, tickets=0 --------------------
__global__ __launch_bounds__(256) void init_k(bf16_t* h_bf, bf16_t* m0,
                                              float* c, float* m, int* cnt) {
    const int idx = blockIdx.x * 256 + threadIdx.x;   // 524288 = B*N*32
    if (idx < 6144) cnt[idx] = 0;                     // 24 dispatches x 256
    h_bf[idx] = (bf16_t)1.f;
    m0[idx]   = (bf16_t)1.f;
    c[idx] = 1.f;
    m[idx] = 1.f;
}

// ---------------- fused split-K GEMM + ticket epilogue ----------------------
// Grid (64 row-tiles, 4 k-slices, B), 256 thr = 4 waves. GEMM phase: R2's
// gemm_splitk verbatim (B LDS-staged per 256-K chunk w/ XOR swizzle, A direct
// global, B loads issued first). Partial 64x64 fp32 tile stored contiguous.
// Last-arriving slice block (device-scope ticket) sums 4 partials and runs
// the gate math (gates1/gates2 body from R2).
// G1: Y = [adj@h | adj@x]    -> c_new (fp32), h_mid panel (w0)
// G2: Y = [adj@hmid | adj@m] -> m_new (fp32 + w0 panel), h_new (hb + hs out)
template <bool ABF, bool G1>
__global__ __launch_bounds__(256, 4) void gg_k(
    const void* __restrict__ Ap,
    const bf16_t* __restrict__ p0, const bf16_t* __restrict__ p1,
    const bf16_t* __restrict__ Wf, const float* __restrict__ bias,
    float* __restrict__ cm, bf16_t* __restrict__ w0,
    bf16_t* __restrict__ hb, float* __restrict__ hs, int t,
    float* __restrict__ Yp, int* __restrict__ cnt)
{
    constexpr int BS1 = G1 ? 384 : 32;
    const int b = blockIdx.z, rt = blockIdx.x, slice = blockIdx.y;
    const int n0 = rt * 64;
    const int tid = threadIdx.x, wave = tid >> 6, lane = tid & 63;
    const int mrow = lane & 15, quad = lane >> 4;
    __shared__ __align__(16) bf16_t Vs[64 * 256];   // 32 KB (Ys overlay later)
    __shared__ bf16_t t0T[32][64];                  // 4 KB
    __shared__ bf16_t t1T[32][64];                  // 4 KB (unused in G1)
    int* lflag = (int*)Vs + 7000;                   // overlay above Ys

    const f32x4 zero4 = {0.f, 0.f, 0.f, 0.f};
    f32x4 acc[4];
#pragma unroll
    for (int i = 0; i < 4; ++i) acc[i] = zero4;
    const int row = n0 + wave * 16 + mrow;
    const size_t arow = ((size_t)b << 24) + (size_t)row * NN;

    // ---- GEMM phase: 4 stages of 256 K ----
    for (int stg = 0; stg < 4; ++stg) {
        const int k0 = slice * 1024 + stg * 256;
        // B loads first (consumed first, by ds_write)
        uint4 brg[8];
        int ldst[8];
#pragma unroll
        for (int rr = 0; rr < 8; ++rr) {
            const int idx = rr * 256 + tid;       // 0..2047 16B-chunks
            const int c = idx >> 5, ch = idx & 31;
            const bf16_t* src = (c >= 32)
                ? p1 + ((size_t)b * BS1 + (c - 32)) * NN
                : p0 + ((size_t)b * 32 + c) * NN;
            brg[rr] = *(const uint4*)(src + k0 + ch * 8);
            ldst[rr] = c * 256 + ((ch ^ (c & 7)) * 8);
        }
        // A fragments (consumed after barrier)
        bf16x8 af[8];
        if constexpr (ABF) {
            const bf16_t* ab = (const bf16_t*)Ap + arow + k0 + quad * 8;
#pragma unroll
            for (int s = 0; s < 8; ++s) af[s] = *(const bf16x8*)(ab + s * 32);
        } else {
            const float* ab = (const float*)Ap + arow + k0 + quad * 8;
#pragma unroll
            for (int s = 0; s < 8; ++s) {
                float4 v0 = *(const float4*)(ab + s * 32);
                float4 v1 = *(const float4*)(ab + s * 32 + 4);
                af[s][0] = (bf16_t)v0.x; af[s][1] = (bf16_t)v0.y;
                af[s][2] = (bf16_t)v0.z; af[s][3] = (bf16_t)v0.w;
                af[s][4] = (bf16_t)v1.x; af[s][5] = (bf16_t)v1.y;
                af[s][6] = (bf16_t)v1.z; af[s][7] = (bf16_t)v1.w;
            }
        }
#pragma unroll
        for (int rr = 0; rr < 8; ++rr) *(uint4*)&Vs[ldst[rr]] = brg[rr];
        __syncthreads();
#pragma unroll
        for (int s = 0; s < 8; ++s) {
#pragma unroll
            for (int ct = 0; ct < 4; ++ct) {
                const int c = ct * 16 + mrow;
                bf16x8 bfr = *(const bf16x8*)&Vs[c * 256 + (((s * 4 + quad) ^ (c & 7)) * 8)];
                acc[ct] = __builtin_amdgcn_mfma_f32_16x16x32_bf16(af[s], bfr, acc[ct], 0, 0, 0);
            }
        }
        __syncthreads();
    }

    // ---- coalesced partial-tile store (LDS transpose, 16 KB contiguous) ----
    float* Ys = (float*)Vs;                         // [64][68]
#pragma unroll
    for (int ct = 0; ct < 4; ++ct)
#pragma unroll
        for (int r = 0; r < 4; ++r)
            Ys[(wave * 16 + quad * 4 + r) * 68 + ct * 16 + mrow] = acc[ct][r];
    __syncthreads();
    {
        float* dst = Yp + ((((size_t)b * 4 + slice) * 64 + rt) << 12);
#pragma unroll
        for (int j = 0; j < 4; ++j) {
            const int f4 = j * 256 + tid;          // float4 index 0..1023
            const int rr2 = f4 >> 4, sg = f4 & 15;
            f32x4 v = *(const f32x4*)&Ys[rr2 * 68 + sg * 4];
            *(f32x4*)(dst + f4 * 4) = v;
        }
    }
    __syncthreads();

    // ---- split-K ticket: last of 4 slice blocks proceeds -------------------
    if (tid == 0) {
        __threadfence();                            // release partial stores
        const int old = atomicAdd(cnt + b * 64 + rt, 1);
        *lflag = (old == 3) ? 1 : 0;
    }
    __syncthreads();
    if (*lflag == 0) return;
    __threadfence();                                // acquire others' partials

    // ---- gate epilogue (this block only; 4 waves x 16 rows) ----------------
    {
        const int rl = wave * 16 + mrow;
        f32x4 h0 = zero4, h1 = zero4, x0 = zero4, x1 = zero4;
#pragma unroll
        for (int sl = 0; sl < 4; ++sl) {
            const float* yr = Yp + ((((size_t)b * 4 + sl) * 64 + rt) << 12) + rl * 64;
            h0 += *(const f32x4*)(yr + quad * 8);
            h1 += *(const f32x4*)(yr + quad * 8 + 4);
            x0 += *(const f32x4*)(yr + 32 + quad * 8);
            x1 += *(const f32x4*)(yr + 32 + quad * 8 + 4);
        }
        bf16x8 ah, ax;   // ah = cols 0..31 (h / h_mid), ax = cols 32..63 (x / m)
#pragma unroll
        for (int j = 0; j < 4; ++j) {
            ah[j] = (bf16_t)h0[j]; ah[j + 4] = (bf16_t)h1[j];
            ax[j] = (bf16_t)x0[j]; ax[j + 4] = (bf16_t)x1[j];
        }
        constexpr int NGI = G1 ? 4 : 3;
        constexpr int GB  = G1 ? 0 : 8;
        float gate[NGI][2][4];
#pragma unroll
        for (int gi = 0; gi < NGI; ++gi) {
            const int ge = GB + 2 * gi, go = ge + 1;
            f32x4 ze[4], zo[4];
#pragma unroll
            for (int ct = 0; ct < 4; ++ct) {
                bf16x8 we = *(const bf16x8*)&Wf[((ge * 4 + ct) * 64 + lane) * 8];
                bf16x8 wo = *(const bf16x8*)&Wf[((go * 4 + ct) * 64 + lane) * 8];
                // G1: even gate acts on x (ax), odd on h (ah).
                // G2: even gate acts on h_mid (ah), odd on m (ax).
                ze[ct] = __builtin_amdgcn_mfma_f32_16x16x32_bf16(G1 ? ax : ah, we, zero4, 0, 0, 0);
                zo[ct] = __builtin_amdgcn_mfma_f32_16x16x32_bf16(G1 ? ah : ax, wo, zero4, 0, 0, 0);
                const float be = bias[ge * 64 + ct * 16 + mrow];
                const float bo = bias[go * 64 + ct * 16 + mrow];
#pragma unroll
                for (int r = 0; r < 4; ++r) { ze[ct][r] += be; zo[ct][r] += bo; }
            }
#pragma unroll
            for (int p = 0; p < 2; ++p)
#pragma unroll
                for (int r = 0; r < 4; ++r) {
                    float s = ze[p][r] * sigm(ze[p + 2][r]) + zo[p][r] * sigm(zo[p + 2][r]);
                    gate[gi][p][r] = (G1 && gi == 2) ? tanh_f(s) : sigm(s);
                }
        }
#pragma unroll
        for (int p = 0; p < 2; ++p)
#pragma unroll
            for (int r = 0; r < 4; ++r) {
                const int rloc = wave * 16 + quad * 4 + r;
                const int rowg = n0 + rloc, col = p * 16 + mrow;
                const size_t ci = ((size_t)b * NN + rowg) * FF + col;
                if constexpr (G1) {
                    float cn = gate[0][p][r] * cm[ci] + gate[1][p][r] * gate[2][p][r];
                    cm[ci] = cn;
                    t0T[col][rloc] = (bf16_t)(gate[3][p][r] * tanh_f(cn));
                } else {
                    const float i2 = gate[0][p][r], gg = gate[1][p][r], o2 = gate[2][p][r];
                    float mn = i2 * cm[ci] + (1.f - i2) * gg;
                    cm[ci] = mn;
                    float hn = mn * o2;
                    hs[(((size_t)b * TT + t) * NN + rowg) * FF + col] = hn;
                    t0T[col][rloc] = (bf16_t)mn;
                    t1T[col][rloc] = (bf16_t)hn;
                }
            }
    }
    __syncthreads();
    // ---- transposed coalesced panel writes: [b][col][n] bf16 ----
    {
        const int col = tid >> 3, seg = tid & 7;
        union { uint4 u; bf16_t h[8]; } o0;
#pragma unroll
        for (int j = 0; j < 8; ++j) o0.h[j] = t0T[col][seg * 8 + j];
        *(uint4*)&w0[((size_t)b * 32 + col) * NN + n0 + seg * 8] = o0.u;
        if constexpr (!G1) {
            union { uint4 u; bf16_t h[8]; } o1;
#pragma unroll
            for (int j = 0; j < 8; ++j) o1.h[j] = t1T[col][seg * 8 + j];
            *(uint4*)&hb[((size_t)b * FF + col) * NN + n0 + seg * 8] = o1.u;
        }
    }
}

// ---------------- tail: last_h / last_c / last_m ----------------------------
__global__ __launch_bounds__(256) void finalize_k(const float* __restrict__ hs,
                                                  const float* __restrict__ c,
                                                  const float* __restrict__ m,
                                                  float* __restrict__ tail) {
    const int idx = blockIdx.x * 256 + threadIdx.x;   // 524288
    const int b = idx >> 17, r = idx & 131071;
    tail[idx] = hs[((size_t)b * TT + (TT - 1)) * 131072 + r];
    tail[524288 + idx] = c[idx];
    tail[1048576 + idx] = m[idx];
}

// ---------------------------------------------------------------------------
extern "C" void kernel_launch(void* const* d_in, const int* in_sizes, int n_in,
                              void* d_out, int out_size, void* d_ws, size_t ws_size,
                              hipStream_t stream) {
    const float* x    = (const float*)d_in[0];   // [4,12,4096,32]
    const float* adj  = (const float*)d_in[1];   // [4,4096,4096]
    const float* W    = (const float*)d_in[2];   // [14,32,64]
    const float* bias = (const float*)d_in[3];   // [14,64]
    float* out = (float*)d_out;

    char* ws = (char*)d_ws;
    size_t off = 0;
    auto carve = [&](size_t bytes) -> void* {
        void* p = ws + off;
        off += (bytes + 255) & ~(size_t)255;
        return p;
    };
    bf16_t* xT    = (bf16_t*)carve((size_t)BB * 384 * NN * 2);   // 12.6 MB
    bf16_t* h_bf  = (bf16_t*)carve((size_t)BB * 32 * NN * 2);    // 1 MB
    bf16_t* hmid  = (bf16_t*)carve((size_t)BB * 32 * NN * 2);    // 1 MB
    bf16_t* mbf0  = (bf16_t*)carve((size_t)BB * 32 * NN * 2);    // 1 MB
    bf16_t* mbf1  = (bf16_t*)carve((size_t)BB * 32 * NN * 2);    // 1 MB
    bf16_t* Wf    = (bf16_t*)carve((size_t)14 * 4 * 64 * 8 * 2);
    float*  cbuf  = (float*)carve((size_t)BB * NN * FF * 4);     // 2 MB
    float*  mbuf  = (float*)carve((size_t)BB * NN * FF * 4);     // 2 MB
    float*  Yp    = (float*)carve((size_t)BB * 4 * 64 * 4096 * 4); // 16.8 MB
    int*    cntb  = (int*)carve((size_t)24 * 256 * 4);           // 24 KB
    const size_t adj_bytes = (size_t)BB * NN * NN * 2;           // 134 MB
    const bool abf = (ws_size >= off + adj_bytes);
    bf16_t* adj_bf = abf ? (bf16_t*)carve(adj_bytes) : nullptr;

    if (abf) conv_adj_k<<<32768, 256, 0, stream>>>(adj, adj_bf);
    make_wfrag_k<<<14, 256, 0, stream>>>(W, Wf);
    xpose_k<<<dim3(64, TT, BB), 256, 0, stream>>>(x, xT);
    init_k<<<2048, 256, 0, stream>>>(h_bf, mbf0, cbuf, mbuf, cntb);

    const dim3 ggrid(64, 4, BB);
    for (int t = 0; t < TT; ++t) {
        const bf16_t* xts = xT + (size_t)t * 32 * NN;
        bf16_t* mrd = (t & 1) ? mbf1 : mbf0;
        bf16_t* mwr = (t & 1) ? mbf0 : mbf1;
        int* c1 = cntb + (t * 2 + 0) * 256;
        int* c2 = cntb + (t * 2 + 1) * 256;
        if (abf) {
            gg_k<true,  true ><<<ggrid, 256, 0, stream>>>(adj_bf, h_bf, xts, Wf, bias,
                                                          cbuf, hmid, nullptr, nullptr, 0, Yp, c1);
            gg_k<true,  false><<<ggrid, 256, 0, stream>>>(adj_bf, hmid, mrd, Wf, bias,
                                                          mbuf, mwr, h_bf, out, t, Yp, c2);
        } else {
            gg_k<false, true ><<<ggrid, 256, 0, stream>>>(adj, h_bf, xts, Wf, bias,
                                                          cbuf, hmid, nullptr, nullptr, 0, Yp, c1);
            gg_k<false, false><<<ggrid, 256, 0, stream>>>(adj, hmid, mrd, Wf, bias,
                                                          mbuf, mwr, h_bf, out, t, Yp, c2);
        }
    }
    finalize_k<<<2048, 256, 0, stream>>>(out, cbuf, mbuf, out + (size_t)BB * TT * NN * FF);
}

// Round 4
// 1308.980 us; speedup vs baseline: 2.2074x; 2.2074x over previous
//
#include <hip/hip_runtime.h>

// ---------------------------------------------------------------------------
// Graph-conv LSTM encoder, B=4 T=12 N=4096 F=32, NG=14 gates.
// R6 = R2 verbatim with ONE delta: split-K reduction via per-slice partial
// buffers (plain coalesced-ish stores, gates sum 4 slices on read) instead of
// fp32 atomicAdd into a shared Y + per-step re-zeroing. No tickets/fences.
// Per step: GEMM1 = adj@[h | x_t], GEMM2 = adj@[h_mid | m], each split-K
// (4 slices); gate kernels consume the 4 partials directly.
// ---------------------------------------------------------------------------

typedef __bf16 bf16_t;
typedef __bf16 bf16x8 __attribute__((ext_vector_type(8)));
typedef float  f32x4  __attribute__((ext_vector_type(4)));

#define DI __device__ __forceinline__

#define BB 4
#define TT 12
#define NN 4096
#define FF 32

DI float sigm(float x)  { return __builtin_amdgcn_rcpf(1.f + __expf(-x)); }
DI float tanh_f(float x){ float e = __expf(2.f * x); return 1.f - 2.f * __builtin_amdgcn_rcpf(e + 1.f); }

// ---------------- adj fp32 -> bf16 (8 elements / thread) --------------------
__global__ __launch_bounds__(256) void conv_adj_k(const float* __restrict__ a,
                                                  bf16_t* __restrict__ o) {
    size_t i = ((size_t)blockIdx.x * 256 + threadIdx.x) * 8;
    float4 v0 = *(const float4*)(a + i);
    float4 v1 = *(const float4*)(a + i + 4);
    union { uint4 u; bf16_t h[8]; } t;
    t.h[0] = (bf16_t)v0.x; t.h[1] = (bf16_t)v0.y; t.h[2] = (bf16_t)v0.z; t.h[3] = (bf16_t)v0.w;
    t.h[4] = (bf16_t)v1.x; t.h[5] = (bf16_t)v1.y; t.h[6] = (bf16_t)v1.z; t.h[7] = (bf16_t)v1.w;
    *(uint4*)(o + i) = t.u;
}

// ---------------- x [B,T,N,F] fp32 -> xT [B, T*F, N] bf16 -------------------
__global__ __launch_bounds__(256) void xpose_k(const float* __restrict__ x,
                                               bf16_t* __restrict__ xT) {
    const int b = blockIdx.z, t = blockIdx.y, n0 = blockIdx.x * 64;
    const int tid = threadIdx.x;
    __shared__ float tile[64][33];
    const float* src = x + (((size_t)(b * TT + t)) * NN + n0) * FF;
#pragma unroll
    for (int rr = 0; rr < 2; ++rr) {
        int idx = rr * 256 + tid;
        int row = idx >> 3, seg = idx & 7;
        float4 v = *(const float4*)(src + row * FF + seg * 4);
        tile[row][seg * 4 + 0] = v.x; tile[row][seg * 4 + 1] = v.y;
        tile[row][seg * 4 + 2] = v.z; tile[row][seg * 4 + 3] = v.w;
    }
    __syncthreads();
    const int f = tid >> 3, seg = tid & 7;
    union { uint4 u; bf16_t h[8]; } o;
#pragma unroll
    for (int j = 0; j < 8; ++j) o.h[j] = (bf16_t)tile[seg * 8 + j][f];
    *(uint4*)&xT[((size_t)(b * 384 + t * FF + f)) * NN + n0 + seg * 8] = o.u;
}

// ---------------- W [14,32,64] fp32 -> MFMA B-fragments bf16 ----------------
__global__ __launch_bounds__(256) void make_wfrag_k(const float* __restrict__ W,
                                                    bf16_t* __restrict__ Wf) {
    const int g = blockIdx.x, tid = threadIdx.x;
    const int ct = tid >> 6, lane = tid & 63;
    const int k0 = (lane >> 4) * 8, col = ct * 16 + (lane & 15);
    union { uint4 u; bf16_t h[8]; } t;
#pragma unroll
    for (int j = 0; j < 8; ++j) t.h[j] = (bf16_t)W[(g * 32 + k0 + j) * 64 + col];
    *(uint4*)&Wf[((g * 4 + ct) * 64 + lane) * 8] = t.u;
}

// ---------------- init: h=c=m=1 ---------------------------------------------
__global__ __launch_bounds__(256) void init_k(bf16_t* h_bf, bf16_t* hm_bf,
                                              float* c, float* m) {
    const int idx = blockIdx.x * 256 + threadIdx.x;   // 524288 = B*N*32
    const int b = idx >> 17, r = idx & 131071;
    h_bf[idx] = (bf16_t)1.f;
    hm_bf[(size_t)b * 262144 + 131072 + r] = (bf16_t)1.f;   // m half
    c[idx] = 1.f;
    m[idx] = 1.f;
}

// ---------------- split-K GEMM: Yp[b][slice] = adj[b] @ [p0 | p1]^T ---------
// Grid (64 row-tiles, 4 k-slices, B). 256 thr = 4 waves, wave handles 16 rows
// x 64 cols. A direct-global (8 bf16x8 loads in flight), B LDS-staged per
// 256-K chunk with XOR swizzle. Epilogue: plain fp32 stores into the slice's
// own partial tile (no atomics, no zeroing).
template <bool ABF, int S, int BS0, int BS1>
__global__ __launch_bounds__(256, 4) void gemm_splitk(const void* __restrict__ Ap,
                                                      const bf16_t* __restrict__ p0,
                                                      const bf16_t* __restrict__ p1,
                                                      float* __restrict__ Yp) {
    const int b = blockIdx.z;
    const int row0 = blockIdx.x * 64;
    const int slice = blockIdx.y;                 // 1024-wide K slice
    const int tid = threadIdx.x, wave = tid >> 6, lane = tid & 63;
    const int mrow = lane & 15, quad = lane >> 4;
    __shared__ __align__(16) bf16_t Vs[64 * 256];
    const f32x4 zero = {0.f, 0.f, 0.f, 0.f};
    f32x4 acc[4];
#pragma unroll
    for (int i = 0; i < 4; ++i) acc[i] = zero;
    const int row = row0 + wave * 16 + mrow;
    const size_t arow = ((size_t)b << 24) + (size_t)row * NN;

    for (int stg = 0; stg < 4; ++stg) {
        const int k0 = slice * 1024 + stg * 256;
        // A fragments for this stage: issued first, complete during staging
        bf16x8 af[8];
        if constexpr (ABF) {
            const bf16_t* ab = (const bf16_t*)Ap + arow + k0 + quad * 8;
#pragma unroll
            for (int s = 0; s < 8; ++s) af[s] = *(const bf16x8*)(ab + s * 32);
        } else {
            const float* ab = (const float*)Ap + arow + k0 + quad * 8;
#pragma unroll
            for (int s = 0; s < 8; ++s) {
                float4 v0 = *(const float4*)(ab + s * 32);
                float4 v1 = *(const float4*)(ab + s * 32 + 4);
                af[s][0] = (bf16_t)v0.x; af[s][1] = (bf16_t)v0.y;
                af[s][2] = (bf16_t)v0.z; af[s][3] = (bf16_t)v0.w;
                af[s][4] = (bf16_t)v1.x; af[s][5] = (bf16_t)v1.y;
                af[s][6] = (bf16_t)v1.z; af[s][7] = (bf16_t)v1.w;
            }
        }
        // stage B panel chunk: 64 cols x 256 k (32 KB), 8 chunks/thread
#pragma unroll
        for (int rr = 0; rr < 8; ++rr) {
            const int idx = rr * 256 + tid;       // 0..2047 16B-chunks
            const int c = idx >> 5, ch = idx & 31;
            const bf16_t* src = (S < 64 && c >= S)
                ? p1 + ((size_t)b * BS1 + (c - S)) * NN
                : p0 + ((size_t)b * BS0 + c) * NN;
            *(uint4*)&Vs[c * 256 + (ch ^ (c & 7)) * 8] =
                *(const uint4*)(src + k0 + ch * 8);
        }
        __syncthreads();
#pragma unroll
        for (int s = 0; s < 8; ++s) {
#pragma unroll
            for (int ct = 0; ct < 4; ++ct) {
                const int c = ct * 16 + mrow;
                bf16x8 bfr = *(const bf16x8*)&Vs[c * 256 + (((s * 4 + quad) ^ (c & 7)) * 8)];
                acc[ct] = __builtin_amdgcn_mfma_f32_16x16x32_bf16(af[s], bfr, acc[ct], 0, 0, 0);
            }
        }
        __syncthreads();
    }
    float* dst = Yp + ((size_t)(b * 4 + slice) * NN) * 64;
#pragma unroll
    for (int ct = 0; ct < 4; ++ct) {
        const int col = ct * 16 + mrow;
#pragma unroll
        for (int r = 0; r < 4; ++r) {
            const int orow = row0 + wave * 16 + quad * 4 + r;
            dst[(size_t)orow * 64 + col] = acc[ct][r];
        }
    }
}

// ---------------- gate kernel 1: gates 0..7 -> c_new, h_mid -----------------
// Yp slices summed on read; cols 0..31 = adj@h, 32..63 = adj@x_t.
__global__ __launch_bounds__(256) void gates1_k(const float* __restrict__ Yp,
                                                const bf16_t* __restrict__ Wf,
                                                const float* __restrict__ bias,
                                                float* __restrict__ c,
                                                bf16_t* __restrict__ hm_bf) {
    const int b = blockIdx.y, n0 = blockIdx.x * 64;
    const int tid = threadIdx.x, wave = tid >> 6, lane = tid & 63;
    const int mrow = lane & 15, quad = lane >> 4;
    const int nw = n0 + wave * 16;
    const f32x4 zero = {0.f, 0.f, 0.f, 0.f};
    const float* ybase = Yp + ((size_t)b * 4 * NN + nw + mrow) * 64;
    f32x4 h0 = zero, h1 = zero, x0 = zero, x1 = zero;
#pragma unroll
    for (int sl = 0; sl < 4; ++sl) {
        const float* yr = ybase + (size_t)sl * NN * 64;
        h0 += *(const f32x4*)(yr + quad * 8);
        h1 += *(const f32x4*)(yr + quad * 8 + 4);
        x0 += *(const f32x4*)(yr + 32 + quad * 8);
        x1 += *(const f32x4*)(yr + 32 + quad * 8 + 4);
    }
    bf16x8 ah, ax;
#pragma unroll
    for (int j = 0; j < 4; ++j) {
        ah[j] = (bf16_t)h0[j]; ah[j + 4] = (bf16_t)h1[j];
        ax[j] = (bf16_t)x0[j]; ax[j + 4] = (bf16_t)x1[j];
    }
    float gate[4][2][4];   // f, i, cg(tanh), o
#pragma unroll
    for (int gi = 0; gi < 4; ++gi) {
        const int ge = 2 * gi, go = ge + 1;
        f32x4 ze[4], zo[4];
#pragma unroll
        for (int ct = 0; ct < 4; ++ct) {
            bf16x8 we = *(const bf16x8*)&Wf[((ge * 4 + ct) * 64 + lane) * 8];
            bf16x8 wo = *(const bf16x8*)&Wf[((go * 4 + ct) * 64 + lane) * 8];
            ze[ct] = __builtin_amdgcn_mfma_f32_16x16x32_bf16(ax, we, zero, 0, 0, 0);
            zo[ct] = __builtin_amdgcn_mfma_f32_16x16x32_bf16(ah, wo, zero, 0, 0, 0);
            const float be = bias[ge * 64 + ct * 16 + mrow];
            const float bo = bias[go * 64 + ct * 16 + mrow];
#pragma unroll
            for (int r = 0; r < 4; ++r) { ze[ct][r] += be; zo[ct][r] += bo; }
        }
#pragma unroll
        for (int p = 0; p < 2; ++p)
#pragma unroll
            for (int r = 0; r < 4; ++r) {
                float s = ze[p][r] * sigm(ze[p + 2][r]) + zo[p][r] * sigm(zo[p + 2][r]);
                gate[gi][p][r] = (gi == 2) ? tanh_f(s) : sigm(s);
            }
    }
    __shared__ bf16_t hmT[32][64];
#pragma unroll
    for (int p = 0; p < 2; ++p)
#pragma unroll
        for (int r = 0; r < 4; ++r) {
            const int row = nw + quad * 4 + r, col = p * 16 + mrow;
            const size_t ci = ((size_t)b * NN + row) * FF + col;
            float cn = gate[0][p][r] * c[ci] + gate[1][p][r] * gate[2][p][r];
            c[ci] = cn;
            hmT[col][wave * 16 + quad * 4 + r] = (bf16_t)(gate[3][p][r] * tanh_f(cn));
        }
    __syncthreads();
    {   // transposed coalesced write: hm_bf[b][col][n]
        const int col = tid >> 3, seg = tid & 7;
        union { uint4 u; bf16_t h[8]; } o;
#pragma unroll
        for (int j = 0; j < 8; ++j) o.h[j] = hmT[col][seg * 8 + j];
        *(uint4*)&hm_bf[((size_t)b * 64 + col) * NN + n0 + seg * 8] = o.u;
    }
}

// ---------------- gate kernel 2: gates 8..13 -> m_new, h_new ----------------
// Yp slices summed on read; cols 0..31 = adj@h_mid, 32..63 = adj@m.
__global__ __launch_bounds__(256) void gates2_k(const float* __restrict__ Yp,
                                                const bf16_t* __restrict__ Wf,
                                                const float* __restrict__ bias,
                                                float* __restrict__ m,
                                                bf16_t* __restrict__ hm_bf,
                                                bf16_t* __restrict__ h_bf,
                                                float* __restrict__ hs, int t) {
    const int b = blockIdx.y, n0 = blockIdx.x * 64;
    const int tid = threadIdx.x, wave = tid >> 6, lane = tid & 63;
    const int mrow = lane & 15, quad = lane >> 4;
    const int nw = n0 + wave * 16;
    const f32x4 zero = {0.f, 0.f, 0.f, 0.f};
    const float* ybase = Yp + ((size_t)b * 4 * NN + nw + mrow) * 64;
    f32x4 h0 = zero, h1 = zero, m0 = zero, m1 = zero;
#pragma unroll
    for (int sl = 0; sl < 4; ++sl) {
        const float* yr = ybase + (size_t)sl * NN * 64;
        h0 += *(const f32x4*)(yr + quad * 8);
        h1 += *(const f32x4*)(yr + quad * 8 + 4);
        m0 += *(const f32x4*)(yr + 32 + quad * 8);
        m1 += *(const f32x4*)(yr + 32 + quad * 8 + 4);
    }
    bf16x8 axh, axm;
#pragma unroll
    for (int j = 0; j < 4; ++j) {
        axh[j] = (bf16_t)h0[j]; axh[j + 4] = (bf16_t)h1[j];
        axm[j] = (bf16_t)m0[j]; axm[j + 4] = (bf16_t)m1[j];
    }
    float gate[3][2][4];   // i2, gg, o2
#pragma unroll
    for (int gi = 0; gi < 3; ++gi) {
        const int ge = 8 + 2 * gi, go = ge + 1;
        f32x4 ze[4], zo[4];
#pragma unroll
        for (int ct = 0; ct < 4; ++ct) {
            bf16x8 we = *(const bf16x8*)&Wf[((ge * 4 + ct) * 64 + lane) * 8];
            bf16x8 wo = *(const bf16x8*)&Wf[((go * 4 + ct) * 64 + lane) * 8];
            ze[ct] = __builtin_amdgcn_mfma_f32_16x16x32_bf16(axh, we, zero, 0, 0, 0);
            zo[ct] = __builtin_amdgcn_mfma_f32_16x16x32_bf16(axm, wo, zero, 0, 0, 0);
            const float be = bias[ge * 64 + ct * 16 + mrow];
            const float bo = bias[go * 64 + ct * 16 + mrow];
#pragma unroll
            for (int r = 0; r < 4; ++r) { ze[ct][r] += be; zo[ct][r] += bo; }
        }
#pragma unroll
        for (int p = 0; p < 2; ++p)
#pragma unroll
            for (int r = 0; r < 4; ++r) {
                float s = ze[p][r] * sigm(ze[p + 2][r]) + zo[p][r] * sigm(zo[p + 2][r]);
                gate[gi][p][r] = sigm(s);
            }
    }
    __shared__ bf16_t mT[32][64];
    __shared__ bf16_t hT[32][64];
#pragma unroll
    for (int p = 0; p < 2; ++p)
#pragma unroll
        for (int r = 0; r < 4; ++r) {
            const int row = nw + quad * 4 + r, col = p * 16 + mrow;
            const size_t ci = ((size_t)b * NN + row) * FF + col;
            const float i2 = gate[0][p][r], gg = gate[1][p][r], o2 = gate[2][p][r];
            float mn = i2 * m[ci] + (1.f - i2) * gg;
            m[ci] = mn;
            float hn = mn * o2;
            hs[(((size_t)b * TT + t) * NN + row) * FF + col] = hn;
            mT[col][wave * 16 + quad * 4 + r] = (bf16_t)mn;
            hT[col][wave * 16 + quad * 4 + r] = (bf16_t)hn;
        }
    __syncthreads();
    {
        const int col = tid >> 3, seg = tid & 7;
        union { uint4 u; bf16_t h[8]; } om, oh;
#pragma unroll
        for (int j = 0; j < 8; ++j) { om.h[j] = mT[col][seg * 8 + j]; oh.h[j] = hT[col][seg * 8 + j]; }
        *(uint4*)&hm_bf[((size_t)b * 64 + 32 + col) * NN + n0 + seg * 8] = om.u;
        *(uint4*)&h_bf[((size_t)b * FF + col) * NN + n0 + seg * 8] = oh.u;
    }
}

// ---------------- tail: last_h / last_c / last_m ----------------------------
__global__ __launch_bounds__(256) void finalize_k(const float* __restrict__ hs,
                                                  const float* __restrict__ c,
                                                  const float* __restrict__ m,
                                                  float* __restrict__ tail) {
    const int idx = blockIdx.x * 256 + threadIdx.x;   // 524288
    const int b = idx >> 17, r = idx & 131071;
    tail[idx] = hs[((size_t)b * TT + (TT - 1)) * 131072 + r];
    tail[524288 + idx] = c[idx];
    tail[1048576 + idx] = m[idx];
}

// ---------------------------------------------------------------------------
extern "C" void kernel_launch(void* const* d_in, const int* in_sizes, int n_in,
                              void* d_out, int out_size, void* d_ws, size_t ws_size,
                              hipStream_t stream) {
    const float* x    = (const float*)d_in[0];   // [4,12,4096,32]
    const float* adj  = (const float*)d_in[1];   // [4,4096,4096]
    const float* W    = (const float*)d_in[2];   // [14,32,64]
    const float* bias = (const float*)d_in[3];   // [14,64]
    float* out = (float*)d_out;

    char* ws = (char*)d_ws;
    size_t off = 0;
    auto carve = [&](size_t bytes) -> void* {
        void* p = ws + off;
        off += (bytes + 255) & ~(size_t)255;
        return p;
    };
    bf16_t* xT    = (bf16_t*)carve((size_t)BB * 384 * NN * 2);   // 12.6 MB
    float*  Yp    = (float*)carve((size_t)BB * 4 * NN * 64 * 4); // 16.8 MB
    bf16_t* h_bf  = (bf16_t*)carve((size_t)BB * FF * NN * 2);    // 1 MB
    bf16_t* hm_bf = (bf16_t*)carve((size_t)BB * 64 * NN * 2);    // 2 MB
    bf16_t* Wf    = (bf16_t*)carve((size_t)14 * 4 * 64 * 8 * 2);
    float*  cbuf  = (float*)carve((size_t)BB * NN * FF * 4);     // 2 MB
    float*  mbuf  = (float*)carve((size_t)BB * NN * FF * 4);     // 2 MB
    const size_t adj_bytes = (size_t)BB * NN * NN * 2;           // 134 MB
    const bool abf = (ws_size >= off + adj_bytes);
    bf16_t* adj_bf = abf ? (bf16_t*)carve(adj_bytes) : nullptr;

    if (abf) conv_adj_k<<<32768, 256, 0, stream>>>(adj, adj_bf);
    make_wfrag_k<<<14, 256, 0, stream>>>(W, Wf);
    xpose_k<<<dim3(64, TT, BB), 256, 0, stream>>>(x, xT);
    init_k<<<2048, 256, 0, stream>>>(h_bf, hm_bf, cbuf, mbuf);

    const dim3 ggrid(64, 4, BB);
    for (int t = 0; t < TT; ++t) {
        const bf16_t* xts = xT + (size_t)t * 32 * NN;
        if (abf) gemm_splitk<true, 32, 32, 384><<<ggrid, 256, 0, stream>>>(adj_bf, h_bf, xts, Yp);
        else     gemm_splitk<false, 32, 32, 384><<<ggrid, 256, 0, stream>>>(adj, h_bf, xts, Yp);
        gates1_k<<<dim3(64, BB), 256, 0, stream>>>(Yp, Wf, bias, cbuf, hm_bf);
        if (abf) gemm_splitk<true, 64, 64, 64><<<ggrid, 256, 0, stream>>>(adj_bf, hm_bf, hm_bf, Yp);
        else     gemm_splitk<false, 64, 64, 64><<<ggrid, 256, 0, stream>>>(adj, hm_bf, hm_bf, Yp);
        gates2_k<<<dim3(64, BB), 256, 0, stream>>>(Yp, Wf, bias, mbuf, hm_bf, h_bf, out, t);
    }
    finalize_k<<<2048, 256, 0, stream>>>(out, cbuf, mbuf, out + (size_t)BB * TT * NN * FF);
}